// Round 15
// baseline (598.428 us; speedup 1.0000x reference)
//
#include <hip/hip_runtime.h>
#include <hip/hip_bf16.h>
#include <math.h>

#define B_N 32
#define S_LEN 4096
#define NTOK (B_N * S_LEN)   // 131072
#define EMB 256
#define NCODE 512
#define WB_STRIDE 98304      // per-batch weight entries (bf16)

typedef __attribute__((ext_vector_type(8))) short short8v;   // 8 bf16 = 4 VGPRs
typedef __attribute__((ext_vector_type(4))) float float4v;
typedef __attribute__((ext_vector_type(2))) float float2v;

__device__ inline ushort f2b(float v) {
    union { __hip_bfloat16 h; ushort u; } cv;
    cv.h = __float2bfloat16(v);   // RNE
    return cv.u;
}
__device__ inline float b2f(ushort u) {
    union { ushort u2[2]; float f; } cv;
    cv.u2[0] = 0; cv.u2[1] = u;
    return cv.f;
}

// ---- ws layout (bytes) ----
constexpr size_t WSB_W   = 0;         // ushort[3145728] generated weights (bf16)
constexpr size_t WSB_CB  = 6291456;   // ushort[131072] codebook bf16
constexpr size_t WSB_CBN = 6553600;   // float[512] codebook sq-norms
constexpr size_t WSB_ACC = 6555648;   // float[513]: [0]=sse, [1..512]=hist

// ---- out layout (floats) ----
constexpr size_t OUT_SCAL = 33554432; // loss, perplexity
constexpr size_t OUT_XR   = 33554434; // x_recon (8B-aligned only -> float2 stores)

// ================= weight generation (all 6 layers, one launch) =================
struct WgenP {
    const float* bw[6]; const float* aw[6]; const float* ab[6];
    int loff[6]; int bstart[7];
};

__global__ __launch_bounds__(256)
void wgen_all(WgenP p, const float* __restrict__ adapt, ushort* __restrict__ wout)
{
    __shared__ float ad[B_N * 64];
    int tid = threadIdx.x;
    for (int i = tid; i < B_N * 64; i += 256) ad[i] = adapt[i];
    __syncthreads();
    int blk = blockIdx.x;
    int l = 0;
    while (l < 5 && blk >= p.bstart[l + 1]) ++l;
    int r = (blk - p.bstart[l]) * 256 + tid;

    float a[64];
    const float4* aw4 = reinterpret_cast<const float4*>(p.aw[l] + (size_t)r * 64);
#pragma unroll
    for (int q = 0; q < 16; ++q) {
        float4 v = aw4[q];
        a[4*q] = v.x; a[4*q+1] = v.y; a[4*q+2] = v.z; a[4*q+3] = v.w;
    }
    float abr = p.ab[l][r], bwr = p.bw[l][r];
    int loff = p.loff[l];
    for (int b2 = 0; b2 < B_N; ++b2) {
        const float* adp = &ad[b2 * 64];
        float s0 = 0.f, s1 = 0.f, s2 = 0.f, s3 = 0.f;
#pragma unroll
        for (int j = 0; j < 64; j += 4) {
            s0 += a[j]   * adp[j];
            s1 += a[j+1] * adp[j+1];
            s2 += a[j+2] * adp[j+2];
            s3 += a[j+3] * adp[j+3];
        }
        float s = ((s0 + s1) + (s2 + s3)) + abr;
        wout[(size_t)b2 * WB_STRIDE + loff + r] = f2b(bwr + s);
    }
}

// ================= codebook prep: norms (fp32) + bf16 copy =================
__global__ __launch_bounds__(256)
void cbprep_kernel(const float* __restrict__ cb, float* __restrict__ cbn,
                   ushort* __restrict__ cbbf)
{
    int c = blockIdx.x * 256 + threadIdx.x;
    if (c >= NCODE) return;
    const float4* c4 = reinterpret_cast<const float4*>(cb) + (size_t)c * 64;
    ushort4* o4 = reinterpret_cast<ushort4*>(cbbf) + (size_t)c * 64;
    float s = 0.f;
#pragma unroll 8
    for (int q = 0; q < 64; ++q) {
        float4 v = c4[q];
        s += v.x*v.x + v.y*v.y + v.z*v.z + v.w*v.w;
        o4[q] = make_ushort4(f2b(v.x), f2b(v.y), f2b(v.z), f2b(v.w));
    }
    cbn[c] = s;
}

// ================= FUSED encoder + VQ + decoder =================
// LDS-traffic-reduced variant (theory: per-CU LDS pipe is the serializer):
//  - VQ: waves partition tokens(2 halves of 32) x codes(2 halves of 256);
//    each B-fragment ds_read feeds TWO token-tile MFMAs (reads halved);
//    cross-half argmin merged via 1KB LDS (val,idx) with lex tie-break.
//  - e1/e2/d0/d2: weights preloaded to regs, A-fragment reads hoisted out
//    of the column loop (e2 64->16, d0 64->32, e1/d2 16->8 reads/wave).
__global__ __launch_bounds__(256, 2)
void encdec_vq(const float* __restrict__ x, const ushort* __restrict__ wbf,
               const float* __restrict__ bb0, const float* __restrict__ bb1,
               const float* __restrict__ bb2, const float* __restrict__ bb3,
               const float* __restrict__ bb4, const float* __restrict__ bb5,
               const ushort* __restrict__ cbbf, const float* __restrict__ cbf,
               const float* __restrict__ cbn,
               float* __restrict__ zq, float* __restrict__ xr,
               float* __restrict__ accg)
{
    __shared__ __align__(16) ushort POOL[25600];
    __shared__ float scbn[NCODE];
    __shared__ int   midx[64];
    __shared__ float mrgv[2][64];
    __shared__ int   mrgi[2][64];

    const int tid = threadIdx.x;
    const int b = blockIdx.y, s0 = blockIdx.x * 64;
    const size_t tok0 = (size_t)b * S_LEN + s0;
    const int lane = tid & 63, w = tid >> 6, r16 = lane & 15, g = lane >> 4;

    ushort* xh1 = POOL;            // stride 136
    ushort* h0  = POOL + 8704;     // stride 72
    ushort* zx  = POOL + 8704;     // stride 264 (32 rows)

    for (int i = tid; i < NCODE; i += 256) scbn[i] = cbn[i];

    { // stage x fp32 -> bf16 LDS [64][136]
        const float4* x4 = reinterpret_cast<const float4*>(x) + tok0 * 32;
#pragma unroll
        for (int it = 0; it < 8; ++it) {
            int idx = tid + it * 256;
            int t = idx >> 5, k4 = idx & 31;
            float4 v = x4[(size_t)t * 32 + k4];
            *reinterpret_cast<ushort4*>(&xh1[t * 136 + 4 * k4]) =
                make_ushort4(f2b(v.x), f2b(v.y), f2b(v.z), f2b(v.w));
        }
    }
    __syncthreads();

    const ushort* wb = wbf + (size_t)b * WB_STRIDE;

    // ---- e0: 128 -> 64, relu; wave owns cols [w*16, +16)   (nt=1, unchanged)
    {
        const ushort* w0 = wb;
        short8v bf[4];
#pragma unroll
        for (int ks = 0; ks < 4; ++ks)
            bf[ks] = *reinterpret_cast<const short8v*>(
                w0 + (size_t)(w*16 + r16) * 128 + ks*32 + g*8);
        float bias = bb0[w*16 + r16];
#pragma unroll
        for (int tt = 0; tt < 4; ++tt) {
            float4v acc = (float4v){0.f, 0.f, 0.f, 0.f};
#pragma unroll
            for (int ks = 0; ks < 4; ++ks) {
                short8v a = *reinterpret_cast<const short8v*>(
                    &xh1[(tt*16 + r16) * 136 + ks*32 + g*8]);
                acc = __builtin_amdgcn_mfma_f32_16x16x32_bf16(a, bf[ks], acc, 0, 0, 0);
            }
#pragma unroll
            for (int reg = 0; reg < 4; ++reg)
                h0[(tt*16 + g*4 + reg) * 72 + w*16 + r16] =
                    f2b(fmaxf(acc[reg] + bias, 0.f));
        }
    }
    __syncthreads();

    // ---- e1: 64 -> 128, relu; bf preloaded, A hoisted (8 LDS reads/wave)
    {
        const ushort* w1 = wb + 8192;
        short8v bf[2][2];
        float bias[2];
#pragma unroll
        for (int nt = 0; nt < 2; ++nt) {
            int col0 = w*32 + nt*16;
            bias[nt] = bb1[col0 + r16];
#pragma unroll
            for (int ks = 0; ks < 2; ++ks)
                bf[nt][ks] = *reinterpret_cast<const short8v*>(
                    w1 + (size_t)(col0 + r16) * 64 + ks*32 + g*8);
        }
#pragma unroll
        for (int tt = 0; tt < 4; ++tt) {
            short8v a0 = *reinterpret_cast<const short8v*>(
                &h0[(tt*16 + r16) * 72 + 0*32 + g*8]);
            short8v a1 = *reinterpret_cast<const short8v*>(
                &h0[(tt*16 + r16) * 72 + 1*32 + g*8]);
#pragma unroll
            for (int nt = 0; nt < 2; ++nt) {
                float4v acc = (float4v){0.f, 0.f, 0.f, 0.f};
                acc = __builtin_amdgcn_mfma_f32_16x16x32_bf16(a0, bf[nt][0], acc, 0, 0, 0);
                acc = __builtin_amdgcn_mfma_f32_16x16x32_bf16(a1, bf[nt][1], acc, 0, 0, 0);
#pragma unroll
                for (int reg = 0; reg < 4; ++reg)
                    xh1[(tt*16 + g*4 + reg) * 136 + w*32 + nt*16 + r16] =
                        f2b(fmaxf(acc[reg] + bias[nt], 0.f));
            }
        }
    }
    __syncthreads();

    // ---- e2: 128 -> 256 in two 32-token halves; bf preloaded, A hoisted
    const int th = w & 1, chf = w >> 1;
    short8v az[2][8];
    {
        const ushort* w2 = wb + 16384;
        short8v bf[4][4];
        float bias[4];
#pragma unroll
        for (int nt = 0; nt < 4; ++nt) {
            int col0 = w*64 + nt*16;
            bias[nt] = bb2[col0 + r16];
#pragma unroll
            for (int ks = 0; ks < 4; ++ks)
                bf[nt][ks] = *reinterpret_cast<const short8v*>(
                    w2 + (size_t)(col0 + r16) * 128 + ks*32 + g*8);
        }
#pragma unroll
        for (int half = 0; half < 2; ++half) {
#pragma unroll
            for (int tt2 = 0; tt2 < 2; ++tt2) {
                int tt = half*2 + tt2;
                short8v a[4];
#pragma unroll
                for (int ks = 0; ks < 4; ++ks)
                    a[ks] = *reinterpret_cast<const short8v*>(
                        &xh1[(tt*16 + r16) * 136 + ks*32 + g*8]);
#pragma unroll
                for (int nt = 0; nt < 4; ++nt) {
                    float4v acc = (float4v){0.f, 0.f, 0.f, 0.f};
#pragma unroll
                    for (int ks = 0; ks < 4; ++ks)
                        acc = __builtin_amdgcn_mfma_f32_16x16x32_bf16(a[ks], bf[nt][ks], acc, 0, 0, 0);
#pragma unroll
                    for (int reg = 0; reg < 4; ++reg)
                        zx[(tt2*16 + g*4 + reg) * 264 + w*64 + nt*16 + r16] =
                            f2b(acc[reg] + bias[nt]);
                }
            }
            __syncthreads();
            if (th == half) {   // wave owns tokens of this half: load 32-token az
#pragma unroll
                for (int tt = 0; tt < 2; ++tt)
#pragma unroll
                    for (int ks = 0; ks < 8; ++ks)
                        az[tt][ks] = *reinterpret_cast<const short8v*>(
                            &zx[(tt*16 + r16) * 264 + ks*32 + g*8]);
            }
            __syncthreads();
        }
    }

    // znorm per owned token (tokens th*32 + tt*16 + r16)
    float znorm[2];
#pragma unroll
    for (int tt = 0; tt < 2; ++tt) {
        float s = 0.f;
#pragma unroll
        for (int ks = 0; ks < 8; ++ks)
#pragma unroll
            for (int j = 0; j < 8; ++j) {
                float zv = b2f((ushort)az[tt][ks][j]);
                s += zv * zv;
            }
        s += __shfl_xor(s, 16);
        s += __shfl_xor(s, 32);
        znorm[tt] = s;
    }

    // ---- VQ: wave owns tokens [th*32,+32) x codes [chf*256,+256)
    float mv[2][4] = {{1e30f,1e30f,1e30f,1e30f},{1e30f,1e30f,1e30f,1e30f}};
    int   mi[2][4] = {{0,0,0,0},{0,0,0,0}};

    ushort* cbA = POOL;
    ushort* cbB = POOL + 8448;
    const int4* cb4 = reinterpret_cast<const int4*>(cbbf);
    const int k8 = tid & 31, cbase = tid >> 5;

    {
        int4 stg[4];
#pragma unroll
        for (int it = 0; it < 4; ++it)
            stg[it] = cb4[(size_t)(cbase + it*8) * 32 + k8];
#pragma unroll
        for (int it = 0; it < 4; ++it)
            *reinterpret_cast<int4*>(&cbA[(cbase + it*8) * 264 + k8*8]) = stg[it];
    }
    __syncthreads();

    for (int ch = 0; ch < 16; ++ch) {
        ushort* cur = (ch & 1) ? cbB : cbA;
        ushort* nxt = (ch & 1) ? cbA : cbB;
        int4 stg[4];
        if (ch < 15) {      // T14: issue loads EARLY
#pragma unroll
            for (int it = 0; it < 4; ++it)
                stg[it] = cb4[(size_t)((ch+1)*32 + cbase + it*8) * 32 + k8];
        }
        if ((ch >> 3) == chf) {   // wave's code half
#pragma unroll
            for (int ct = 0; ct < 2; ++ct) {
                float4v d0 = (float4v){0.f, 0.f, 0.f, 0.f};
                float4v d1 = (float4v){0.f, 0.f, 0.f, 0.f};
#pragma unroll
                for (int ks = 0; ks < 8; ++ks) {
                    short8v bb = *reinterpret_cast<const short8v*>(
                        &cur[(ct*16 + r16) * 264 + ks*32 + g*8]);
                    d0 = __builtin_amdgcn_mfma_f32_16x16x32_bf16(az[0][ks], bb, d0, 0, 0, 0);
                    d1 = __builtin_amdgcn_mfma_f32_16x16x32_bf16(az[1][ks], bb, d1, 0, 0, 0);
                }
                int c0 = ch*32 + ct*16 + r16;
                float cn = scbn[c0];
#pragma unroll
                for (int reg = 0; reg < 4; ++reg) {
                    float dd0 = cn - 2.0f * d0[reg];
                    if (dd0 < mv[0][reg]) { mv[0][reg] = dd0; mi[0][reg] = c0; }
                    float dd1 = cn - 2.0f * d1[reg];
                    if (dd1 < mv[1][reg]) { mv[1][reg] = dd1; mi[1][reg] = c0; }
                }
            }
        }
        if (ch < 15) {      // T14: write LATE
#pragma unroll
            for (int it = 0; it < 4; ++it)
                *reinterpret_cast<int4*>(&nxt[(cbase + it*8) * 264 + k8*8]) = stg[it];
        }
        __syncthreads();
    }

    // butterfly over 16 code-lanes (lex min == first-index within half)
#pragma unroll
    for (int m = 1; m <= 8; m <<= 1) {
#pragma unroll
        for (int tt = 0; tt < 2; ++tt)
#pragma unroll
            for (int reg = 0; reg < 4; ++reg) {
                float ov = __shfl_xor(mv[tt][reg], m);
                int   oi = __shfl_xor(mi[tt][reg], m);
                if (ov < mv[tt][reg] || (ov == mv[tt][reg] && oi < mi[tt][reg])) {
                    mv[tt][reg] = ov; mi[tt][reg] = oi;
                }
            }
    }
    // znorm for token g*4+reg lives at lane (g*4+reg); fetch all-lanes
    float znt[2][4];
#pragma unroll
    for (int tt = 0; tt < 2; ++tt)
#pragma unroll
        for (int reg = 0; reg < 4; ++reg)
            znt[tt][reg] = __shfl(znorm[tt], 4*g + reg);
    if (r16 == 0) {
#pragma unroll
        for (int tt = 0; tt < 2; ++tt)
#pragma unroll
            for (int reg = 0; reg < 4; ++reg) {
                int t = th*32 + tt*16 + g*4 + reg;
                mrgv[chf][t] = znt[tt][reg] + mv[tt][reg];
                mrgi[chf][t] = mi[tt][reg];
            }
    }
    __syncthreads();

    // merge code-halves; write midx, hist, sse
    if (tid < 64) {
        float v0 = mrgv[0][tid], v1 = mrgv[1][tid];
        int   i0 = mrgi[0][tid], i1 = mrgi[1][tid];
        bool take1 = (v1 < v0);            // i1 > i0 always, so tie -> half 0
        float vf = take1 ? v1 : v0;
        int   ifn = take1 ? i1 : i0;
        midx[tid] = ifn;
        atomicAdd(&accg[1 + ifn], 1.0f);
        float c = vf;
#pragma unroll
        for (int m = 1; m < 64; m <<= 1) c += __shfl_xor(c, m);
        if (tid == 0) atomicAdd(&accg[0], c);
    }
    __syncthreads();

    // dec gather q rows bf16 -> qbuf (POOL @0, stride 264)
    {
#pragma unroll
        for (int it = 0; it < 8; ++it) {
            int idx = tid + it * 256;
            int t = idx >> 5, kk = idx & 31;
            reinterpret_cast<int4*>(POOL)[t * 33 + kk] =
                cb4[(size_t)midx[t] * 32 + kk];
        }
    }

    // z_q = q (fp32 codebook gather), NT streamed
    float4v* zq4 = reinterpret_cast<float4v*>(zq) + tok0 * 64;
    const float4* cf4 = reinterpret_cast<const float4*>(cbf);
#pragma unroll
    for (int it = 0; it < 16; ++it) {
        int idx = tid + it * 256;
        int t = idx >> 6, k4 = idx & 63;
        float4 q = cf4[(size_t)midx[t] * 64 + k4];
        float4v ov = (float4v){q.x, q.y, q.z, q.w};
        __builtin_nontemporal_store(ov, &zq4[(size_t)t * 64 + k4]);
    }
    __syncthreads();   // qbuf complete

    // ================= decoder phase =================
    ushort* qbuf = POOL;           // [64][264]
    ushort* h3   = POOL + 16896;   // [64][136]
    ushort* h4   = POOL;           // [64][72]   (qbuf dead after d0)
    float*  xrb  = reinterpret_cast<float*>(POOL + 4608);  // [64][132] fp32

    // d0: 256 -> 128, relu; bf preloaded, A hoisted (32 LDS reads/wave)
    {
        const ushort* wD = wb + 49152;
        short8v bf[2][8];
        float bias[2];
#pragma unroll
        for (int nt = 0; nt < 2; ++nt) {
            int col0 = w*32 + nt*16;
            bias[nt] = bb3[col0 + r16];
#pragma unroll
            for (int ks = 0; ks < 8; ++ks)
                bf[nt][ks] = *reinterpret_cast<const short8v*>(
                    wD + (size_t)(col0 + r16) * 256 + ks*32 + g*8);
        }
#pragma unroll
        for (int tt = 0; tt < 4; ++tt) {
            short8v a[8];
#pragma unroll
            for (int ks = 0; ks < 8; ++ks)
                a[ks] = *reinterpret_cast<const short8v*>(
                    &qbuf[(tt*16 + r16) * 264 + ks*32 + g*8]);
#pragma unroll
            for (int nt = 0; nt < 2; ++nt) {
                float4v acc = (float4v){0.f, 0.f, 0.f, 0.f};
#pragma unroll
                for (int ks = 0; ks < 8; ++ks)
                    acc = __builtin_amdgcn_mfma_f32_16x16x32_bf16(a[ks], bf[nt][ks], acc, 0, 0, 0);
#pragma unroll
                for (int reg = 0; reg < 4; ++reg)
                    h3[(tt*16 + g*4 + reg) * 136 + w*32 + nt*16 + r16] =
                        f2b(fmaxf(acc[reg] + bias[nt], 0.f));
            }
        }
    }
    __syncthreads();
    // d1: 128 -> 64, relu (nt=1, unchanged)
    {
        const ushort* wD = wb + 81920;
        float bias = bb4[w*16 + r16];
        short8v bf[4];
#pragma unroll
        for (int ks = 0; ks < 4; ++ks)
            bf[ks] = *reinterpret_cast<const short8v*>(
                wD + (size_t)(w*16 + r16) * 128 + ks*32 + g*8);
#pragma unroll
        for (int tt = 0; tt < 4; ++tt) {
            float4v acc = (float4v){0.f, 0.f, 0.f, 0.f};
#pragma unroll
            for (int ks = 0; ks < 4; ++ks) {
                short8v a = *reinterpret_cast<const short8v*>(
                    &h3[(tt*16 + r16) * 136 + ks*32 + g*8]);
                acc = __builtin_amdgcn_mfma_f32_16x16x32_bf16(a, bf[ks], acc, 0, 0, 0);
            }
#pragma unroll
            for (int reg = 0; reg < 4; ++reg)
                h4[(tt*16 + g*4 + reg) * 72 + w*16 + r16] =
                    f2b(fmaxf(acc[reg] + bias, 0.f));
        }
    }
    __syncthreads();
    // d2: 64 -> 128, sigmoid; bf preloaded, A hoisted (8 LDS reads/wave)
    {
        const ushort* wD = wb + 90112;
        short8v bf[2][2];
        float bias[2];
#pragma unroll
        for (int nt = 0; nt < 2; ++nt) {
            int col0 = w*32 + nt*16;
            bias[nt] = bb5[col0 + r16];
#pragma unroll
            for (int ks = 0; ks < 2; ++ks)
                bf[nt][ks] = *reinterpret_cast<const short8v*>(
                    wD + (size_t)(col0 + r16) * 64 + ks*32 + g*8);
        }
#pragma unroll
        for (int tt = 0; tt < 4; ++tt) {
            short8v a0 = *reinterpret_cast<const short8v*>(
                &h4[(tt*16 + r16) * 72 + 0*32 + g*8]);
            short8v a1 = *reinterpret_cast<const short8v*>(
                &h4[(tt*16 + r16) * 72 + 1*32 + g*8]);
#pragma unroll
            for (int nt = 0; nt < 2; ++nt) {
                float4v acc = (float4v){0.f, 0.f, 0.f, 0.f};
                acc = __builtin_amdgcn_mfma_f32_16x16x32_bf16(a0, bf[nt][0], acc, 0, 0, 0);
                acc = __builtin_amdgcn_mfma_f32_16x16x32_bf16(a1, bf[nt][1], acc, 0, 0, 0);
#pragma unroll
                for (int reg = 0; reg < 4; ++reg) {
                    float v = acc[reg] + bias[nt];
                    xrb[(tt*16 + g*4 + reg) * 132 + w*32 + nt*16 + r16] =
                        1.0f / (1.0f + expf(-v));
                }
            }
        }
    }
    __syncthreads();
    {   // vectorized store (xr base only 8B-aligned -> float2)
        float2v* xr2 = reinterpret_cast<float2v*>(xr) + tok0 * 64;
#pragma unroll
        for (int it = 0; it < 16; ++it) {
            int idx = tid + it * 256;
            int t = idx >> 6, k2 = idx & 63;
            float2v ov = (float2v){xrb[t * 132 + 2*k2], xrb[t * 132 + 2*k2 + 1]};
            __builtin_nontemporal_store(ov, &xr2[(size_t)t * 64 + k2]);
        }
    }
}

// ================= finalize scalars =================
__global__ __launch_bounds__(512)
void finalize_kernel(const float* __restrict__ acc, float* __restrict__ out_scal)
{
    __shared__ float red[512];
    int tid = threadIdx.x;
    float p = acc[1 + tid] * (1.0f / (float)NTOK);
    red[tid] = p * logf(p + 1e-10f);
    __syncthreads();
    for (int s = 256; s > 0; s >>= 1) {
        if (tid < s) red[tid] += red[tid + s];
        __syncthreads();
    }
    if (tid == 0) {
        out_scal[0] = 1.25f * (acc[0] * (1.0f / 33554432.0f)); // q_latent + 0.25*e_latent
        out_scal[1] = expf(-red[0]);
    }
}

// ================= launch =================
extern "C" void kernel_launch(void* const* d_in, const int* in_sizes, int n_in,
                              void* d_out, int out_size, void* d_ws, size_t ws_size,
                              hipStream_t stream)
{
    (void)in_sizes; (void)n_in; (void)out_size; (void)ws_size;
    const float* x     = (const float*)d_in[0];
    const float* adapt = (const float*)d_in[1];
    const float* bw[6]  = {(const float*)d_in[2],  (const float*)d_in[6],  (const float*)d_in[10],
                           (const float*)d_in[14], (const float*)d_in[18], (const float*)d_in[22]};
    const float* bbp[6] = {(const float*)d_in[3],  (const float*)d_in[7],  (const float*)d_in[11],
                           (const float*)d_in[15], (const float*)d_in[19], (const float*)d_in[23]};
    const float* aw[6]  = {(const float*)d_in[4],  (const float*)d_in[8],  (const float*)d_in[12],
                           (const float*)d_in[16], (const float*)d_in[20], (const float*)d_in[24]};
    const float* ab[6]  = {(const float*)d_in[5],  (const float*)d_in[9],  (const float*)d_in[13],
                           (const float*)d_in[17], (const float*)d_in[21], (const float*)d_in[25]};
    const float* cb = (const float*)d_in[26];

    char*   wsb  = (char*)d_ws;
    ushort* wbf  = (ushort*)(wsb + WSB_W);
    ushort* cbbf = (ushort*)(wsb + WSB_CB);
    float*  cbn  = (float*) (wsb + WSB_CBN);
    float*  acc  = (float*) (wsb + WSB_ACC);

    float*  out  = (float*)d_out;
    float*  zf   = out;              // z_q fp32
    float*  scal = out + OUT_SCAL;
    float*  xr   = out + OUT_XR;     // x_recon fp32

    hipMemsetAsync(acc, 0, 513 * sizeof(float), stream);

    WgenP p;
    const int loff[6]   = {0, 8192, 16384, 49152, 81920, 90112};
    const int bstart[7] = {0, 32, 64, 192, 320, 352, 384};
    for (int l = 0; l < 6; ++l) {
        p.bw[l] = bw[l]; p.aw[l] = aw[l]; p.ab[l] = ab[l]; p.loff[l] = loff[l];
    }
    for (int i = 0; i < 7; ++i) p.bstart[i] = bstart[i];

    wgen_all<<<384, 256, 0, stream>>>(p, adapt, wbf);
    cbprep_kernel<<<2, 256, 0, stream>>>(cb, cbn, cbbf);
    encdec_vq<<<dim3(64, 32), 256, 0, stream>>>(x, wbf,
                                                bbp[0], bbp[1], bbp[2],
                                                bbp[3], bbp[4], bbp[5],
                                                cbbf, cb, cbn, zf, xr, acc);
    finalize_kernel<<<1, 512, 0, stream>>>(acc, scal);
}